// Round 3
// baseline (249.212 us; speedup 1.0000x reference)
//
#include <hip/hip_runtime.h>

#define NUM_SEGS 1024
#define CHUNK_LOG 13
#define CHUNK (1 << CHUNK_LOG)   // 8192 elements per chunk
#define SUBCH 4                  // chunks per block (superchunk = 32768)
#define SUPER (CHUNK * SUBCH)
#define BLK 512                  // 8 waves/block; 2 blocks/CU resident
#define NWAVE (BLK / 64)
#define SEGBLK 256

__device__ __forceinline__ float waveReduceSumF(float v) {
#pragma unroll
    for (int off = 32; off > 0; off >>= 1) v += __shfl_down(v, off, 64);
    return v;
}
__device__ __forceinline__ double waveReduceSumD(double v) {
#pragma unroll
    for (int off = 32; off > 0; off >>= 1) v += __shfl_down(v, off, 64);
    return v;
}
__device__ __forceinline__ unsigned waveReduceSumU(unsigned v) {
#pragma unroll
    for (int off = 32; off > 0; off >>= 1) v += __shfl_down(v, off, 64);
    return v;
}
__device__ __forceinline__ int waveReduceMaxI(int v) {
#pragma unroll
    for (int off = 32; off > 0; off >>= 1) {
        const int o = __shfl_down(v, off, 64);
        v = o > v ? o : v;
    }
    return v;
}

// ---------------- init: zero accumulators (ws is poisoned 0xAA every call) ---
__global__ void init_kernel(unsigned* __restrict__ seg_cnt,
                            float* __restrict__ csums, int nChunks,
                            unsigned* __restrict__ obs,
                            double* __restrict__ loss1,
                            double* __restrict__ loss2,
                            unsigned* __restrict__ done) {
    const int t = blockIdx.x * blockDim.x + threadIdx.x;
    if (t < NUM_SEGS) seg_cnt[t] = 0u;
    if (t < nChunks) csums[t] = 0.f;
    if (t == 0) { obs[0] = 0u; loss1[0] = 0.0; loss2[0] = 0.0; done[0] = 0u; }
}

// ---------------- pass 1: barrier-free streaming ----------------------------
// Per wave: contiguous 1024-elem slice of each of the 4 chunks, fully unrolled
// (16 independent float4/int4 load triples -> deep vmcnt pipeline). Chunk sums
// flushed per-wave via global float atomicAdd (no block reduce, no barriers in
// the hot loop). No last-index tracking at all (seg pass finds it backward).
__global__ __launch_bounds__(BLK, 4) void pass1_kernel(
    const float* __restrict__ outs, const int* __restrict__ te,
    const int* __restrict__ tt, int N, int nChunks,
    float* __restrict__ csums, unsigned* __restrict__ seg_cnt,
    unsigned* __restrict__ obs, double* __restrict__ loss1) {
    __shared__ unsigned hist[NUM_SEGS];
    __shared__ float redF[NWAVE];
    __shared__ unsigned redU[NWAVE];

    for (int t = threadIdx.x; t < NUM_SEGS; t += BLK) hist[t] = 0u;
    __syncthreads();

    const int lane = threadIdx.x & 63;
    const int wid = threadIdx.x >> 6;
    const int superBase = blockIdx.x * SUPER;

    float sE[SUBCH] = {0.f, 0.f, 0.f, 0.f};
    float sumOE = 0.f;
    unsigned cntE = 0u;

    if (superBase + SUPER <= N) {
        // fast path: full superchunk. Wave wid owns [k*CHUNK + wid*1024, +1024)
        // in each chunk k: 4 iterations of 64 lanes x float4.
#pragma unroll
        for (int u = 0; u < SUBCH * 4; ++u) {
            const int k = u >> 2, it = u & 3;
            const int i = superBase + (k << CHUNK_LOG) + (wid << 10) + (it << 8) +
                          (lane << 2);
            const float4 o = *reinterpret_cast<const float4*>(outs + i);
            const int4 ev = *reinterpret_cast<const int4*>(te + i);
            const int4 sv = *reinterpret_cast<const int4*>(tt + i);
            const float e0 = __expf(o.x), e1 = __expf(o.y);
            const float e2 = __expf(o.z), e3 = __expf(o.w);
            sE[k] += (e0 + e1) + (e2 + e3);
            const int s0 = sv.x < 0 ? -sv.x : sv.x;
            const int s1 = sv.y < 0 ? -sv.y : sv.y;
            const int s2 = sv.z < 0 ? -sv.z : sv.z;
            const int s3 = sv.w < 0 ? -sv.w : sv.w;
            if (ev.x > 0) { cntE++; sumOE += o.x; atomicAdd(&hist[s0], 1u); }
            if (ev.y > 0) { cntE++; sumOE += o.y; atomicAdd(&hist[s1], 1u); }
            if (ev.z > 0) { cntE++; sumOE += o.z; atomicAdd(&hist[s2], 1u); }
            if (ev.w > 0) { cntE++; sumOE += o.w; atomicAdd(&hist[s3], 1u); }
        }
    } else {
        // tail path (not hit for N = 16M)
        for (int k = 0; k < SUBCH; ++k) {
            const int cbase = superBase + k * CHUNK;
            if (cbase >= N) break;
            const int end = (cbase + CHUNK < N) ? cbase + CHUNK : N;
            for (int i = cbase + (int)threadIdx.x; i < end; i += BLK) {
                const float o = outs[i];
                const int e = te[i];
                int s = tt[i]; s = s < 0 ? -s : s;
                sE[k] += __expf(o);
                if (e > 0) { cntE++; sumOE += o; atomicAdd(&hist[s], 1u); }
            }
        }
    }

    // per-wave chunk-sum flush: one float atomic per (wave, chunk)
#pragma unroll
    for (int k = 0; k < SUBCH; ++k) {
        const float w = waveReduceSumF(sE[k]);
        if (lane == 0) {
            const int cidx = (superBase >> CHUNK_LOG) + k;
            if (cidx < nChunks) atomicAdd(&csums[cidx], w);
        }
    }

    __syncthreads();  // the only block barrier: hist complete

    for (int t = threadIdx.x; t < NUM_SEGS; t += BLK) {
        const unsigned h = hist[t];
        if (h) atomicAdd(&seg_cnt[t], h);
    }

    // block-reduce E stats
    const float wOE = waveReduceSumF(sumOE);
    const unsigned wC = waveReduceSumU(cntE);
    if (lane == 0) { redF[wid] = wOE; redU[wid] = wC; }
    __syncthreads();
    if (threadIdx.x == 0) {
        float oe = 0.f; unsigned c = 0u;
#pragma unroll
        for (int j = 0; j < NWAVE; ++j) { oe += redF[j]; c += redU[j]; }
        atomicAdd(loss1, (double)oe);
        atomicAdd(obs, c);
    }
}

// ---------------- pass 2 (fused): backward last-idx search + prefix + finalize
// Block t: scan chunks from the end until segment t is found (random data:
// always the last chunk, L2-hot for all 1024 blocks). Then fp64 prefix over
// csums[0..c), fp32 in-chunk exp-sum to LI, V*cnt, ticket-finalize.
__global__ __launch_bounds__(SEGBLK) void seg_final_kernel(
    const float* __restrict__ outs, const int* __restrict__ tt,
    const float* __restrict__ csums, const unsigned* __restrict__ seg_cnt,
    const double* __restrict__ loss1, double* __restrict__ loss2,
    const unsigned* __restrict__ obs, unsigned* __restrict__ done,
    float* __restrict__ out, int N, int nChunks) {
    __shared__ double redD[SEGBLK / 64];
    __shared__ float redF[SEGBLK / 64];
    __shared__ int redI[SEGBLK / 64];
    __shared__ int s_li;

    const int t = blockIdx.x;
    const unsigned cnt = seg_cnt[t];
    const int lane = threadIdx.x & 63, wid = threadIdx.x >> 6;

    if (cnt != 0u) {  // cnt==0 segments contribute 0
        // ---- backward search for the last occurrence of segment t ----
        int c = nChunks - 1;
        int LI = -1;
        for (;;) {
            const int base = c << CHUNK_LOG;
            const int end = (base + CHUNK < N) ? base + CHUNK : N;
            const int span = end - base;
            const int qspan = span & ~3;  // int4-aligned portion
            int li = -1;
            for (int i = base + ((int)threadIdx.x << 2); i < base + qspan;
                 i += SEGBLK * 4) {
                const int4 sv = *reinterpret_cast<const int4*>(tt + i);
                const int s0 = sv.x < 0 ? -sv.x : sv.x;
                const int s1 = sv.y < 0 ? -sv.y : sv.y;
                const int s2 = sv.z < 0 ? -sv.z : sv.z;
                const int s3 = sv.w < 0 ? -sv.w : sv.w;
                if (s3 == t) li = i + 3;
                else if (s2 == t) li = i + 2;
                else if (s1 == t) li = i + 1;
                else if (s0 == t) li = i;
                // ascending i => later assignment always larger
            }
            for (int i = base + qspan + (int)threadIdx.x; i < end; i += SEGBLK) {
                int s = tt[i]; s = s < 0 ? -s : s;
                if (s == t && i > li) li = i;
            }
            li = waveReduceMaxI(li);
            if (lane == 0) redI[wid] = li;
            __syncthreads();
            if (threadIdx.x == 0) {
                int m = redI[0];
#pragma unroll
                for (int j = 1; j < SEGBLK / 64; ++j) m = redI[j] > m ? redI[j] : m;
                s_li = m;
            }
            __syncthreads();
            LI = s_li;
            if (LI >= 0 || --c < 0) break;
        }

        if (LI >= 0) {
            // fp64 exclusive prefix of chunk sums [0, c)
            double p = 0.0;
            for (int j = threadIdx.x; j < c; j += SEGBLK) p += (double)csums[j];
            p = waveReduceSumD(p);
            if (lane == 0) redD[wid] = p;

            // fp32 in-chunk exp-sum up to and including LI
            const int base = c << CHUNK_LOG;
            float fs = 0.f;
            for (int i = base + (int)threadIdx.x; i <= LI; i += SEGBLK)
                fs += __expf(outs[i]);
            fs = waveReduceSumF(fs);
            if (lane == 0) redF[wid] = fs;
            __syncthreads();
            if (threadIdx.x == 0) {
                double pre = 0.0;
                float fsum = 0.f;
#pragma unroll
                for (int j = 0; j < SEGBLK / 64; ++j) { pre += redD[j]; fsum += redF[j]; }
                double sm = log(pre + (double)fsum);  // monotone cumsum => max at LI
                if (sm < 0.0) sm = 0.0;               // jnp.maximum(..., 0.0)
                atomicAdd(loss2, sm * (double)cnt);
            }
        }
    }

    // done-ticket: last block finalizes (no separate final kernel)
    if (threadIdx.x == 0) {
        __threadfence();
        const unsigned d = atomicAdd(done, 1u);
        if (d == (unsigned)(gridDim.x - 1)) {
            const double l2 = atomicAdd(loss2, 0.0);            // atomic read
            const double l1 = *(volatile const double*)loss1;   // prior dispatch
            const unsigned o = *(volatile const unsigned*)obs;
            out[0] = (float)((l2 - l1) / (double)o);
        }
    }
}

extern "C" void kernel_launch(void* const* d_in, const int* in_sizes, int n_in,
                              void* d_out, int out_size, void* d_ws, size_t ws_size,
                              hipStream_t stream) {
    const float* outs = (const float*)d_in[0];
    const int* te = (const int*)d_in[1];
    const int* tt = (const int*)d_in[2];
    const int N = in_sizes[0];
    float* out = (float*)d_out;

    const int nChunks = (N + CHUNK - 1) / CHUNK;

    char* ws = (char*)d_ws;
    double* d_loss1 = (double*)ws;                        // 1 double
    double* d_loss2 = d_loss1 + 1;                        // 1 double
    float* d_csums = (float*)(ws + 16);                   // nChunks floats
    unsigned* d_segcnt = (unsigned*)(d_csums + nChunks);  // NUM_SEGS u32
    unsigned* d_obs = d_segcnt + NUM_SEGS;
    unsigned* d_done = d_obs + 1;

    const int initThreads = (nChunks > NUM_SEGS ? nChunks : NUM_SEGS);
    init_kernel<<<(initThreads + 255) / 256, 256, 0, stream>>>(
        d_segcnt, d_csums, nChunks, d_obs, d_loss1, d_loss2, d_done);
    const int nSuper = (N + SUPER - 1) / SUPER;
    pass1_kernel<<<nSuper, BLK, 0, stream>>>(outs, te, tt, N, nChunks, d_csums,
                                             d_segcnt, d_obs, d_loss1);
    seg_final_kernel<<<NUM_SEGS, SEGBLK, 0, stream>>>(
        outs, tt, d_csums, d_segcnt, d_loss1, d_loss2, d_obs, d_done, out, N,
        nChunks);
}

// Round 4
// 238.858 us; speedup vs baseline: 1.0433x; 1.0433x over previous
//
#include <hip/hip_runtime.h>

#define NUM_SEGS 1024
#define CHUNK_LOG 13
#define CHUNK (1 << CHUNK_LOG)   // 8192 elements per chunk
#define SUBCH 2                  // chunks per block (superchunk = 16384)
#define SUPER (CHUNK * SUBCH)
#define BLK 1024                 // 16 waves/block; 2 blocks/CU resident -> 100% occ cap
#define NWAVE (BLK / 64)
#define SEGBLK 256

__device__ __forceinline__ float waveReduceSumF(float v) {
#pragma unroll
    for (int off = 32; off > 0; off >>= 1) v += __shfl_down(v, off, 64);
    return v;
}
__device__ __forceinline__ double waveReduceSumD(double v) {
#pragma unroll
    for (int off = 32; off > 0; off >>= 1) v += __shfl_down(v, off, 64);
    return v;
}
__device__ __forceinline__ unsigned waveReduceSumU(unsigned v) {
#pragma unroll
    for (int off = 32; off > 0; off >>= 1) v += __shfl_down(v, off, 64);
    return v;
}
__device__ __forceinline__ int waveReduceMaxI(int v) {
#pragma unroll
    for (int off = 32; off > 0; off >>= 1) {
        const int o = __shfl_down(v, off, 64);
        v = o > v ? o : v;
    }
    return v;
}

// ---------------- init: zero accumulators (ws is poisoned 0xAA every call) ---
__global__ void init_kernel(unsigned* __restrict__ seg_cnt,
                            float* __restrict__ csums, int nChunks,
                            unsigned* __restrict__ obs,
                            double* __restrict__ loss1,
                            double* __restrict__ loss2,
                            unsigned* __restrict__ done) {
    const int t = blockIdx.x * blockDim.x + threadIdx.x;
    if (t < NUM_SEGS) seg_cnt[t] = 0u;
    if (t < nChunks) csums[t] = 0.f;
    if (t == 0) { obs[0] = 0u; loss1[0] = 0.0; loss2[0] = 0.0; done[0] = 0u; }
}

// ---------------- pass 1: barrier-free streaming with register prefetch -----
// Each thread: 4 float4/int4-triple iterations (16 elems), double-buffered in
// registers so iteration u+1's 3 loads are issued BEFORE processing iteration
// u -> >=3 loads in flight per wave at all times (no vmcnt(0) serialization).
// Chunk sums flushed per-wave via global float atomicAdd; single block barrier.
__global__ __launch_bounds__(BLK, 8) void pass1_kernel(
    const float* __restrict__ outs, const int* __restrict__ te,
    const int* __restrict__ tt, int N, int nChunks,
    float* __restrict__ csums, unsigned* __restrict__ seg_cnt,
    unsigned* __restrict__ obs, double* __restrict__ loss1) {
    __shared__ unsigned hist[NUM_SEGS];
    __shared__ float redF[NWAVE];
    __shared__ unsigned redU[NWAVE];

    for (int t = threadIdx.x; t < NUM_SEGS; t += BLK) hist[t] = 0u;
    __syncthreads();

    const int lane = threadIdx.x & 63;
    const int wid = threadIdx.x >> 6;
    const int superBase = blockIdx.x * SUPER;

    float sE0 = 0.f, sE1 = 0.f;   // chunk 0 / chunk 1 exp-sums
    float sumOE = 0.f;
    unsigned cntE = 0u;

    if (superBase + SUPER <= N) {
        // fast path: 4 iterations of BLK*4 = 4096 elems; u=0,1 -> chunk 0,
        // u=2,3 -> chunk 1. Register double-buffer: load u+1 before process u.
        const int i0 = superBase + ((int)threadIdx.x << 2);
        float4 oc = *reinterpret_cast<const float4*>(outs + i0);
        int4 ec = *reinterpret_cast<const int4*>(te + i0);
        int4 sc = *reinterpret_cast<const int4*>(tt + i0);
#pragma unroll
        for (int u = 0; u < 4; ++u) {
            float4 on; int4 en, sn;
            if (u < 3) {
                const int i = i0 + (u + 1) * (BLK * 4);
                on = *reinterpret_cast<const float4*>(outs + i);
                en = *reinterpret_cast<const int4*>(te + i);
                sn = *reinterpret_cast<const int4*>(tt + i);
            }
            const float e0 = __expf(oc.x), e1 = __expf(oc.y);
            const float e2 = __expf(oc.z), e3 = __expf(oc.w);
            const float ps = (e0 + e1) + (e2 + e3);
            if (u < 2) sE0 += ps; else sE1 += ps;  // compile-time select
            const int s0 = sc.x < 0 ? -sc.x : sc.x;
            const int s1 = sc.y < 0 ? -sc.y : sc.y;
            const int s2 = sc.z < 0 ? -sc.z : sc.z;
            const int s3 = sc.w < 0 ? -sc.w : sc.w;
            if (ec.x > 0) { cntE++; sumOE += oc.x; atomicAdd(&hist[s0], 1u); }
            if (ec.y > 0) { cntE++; sumOE += oc.y; atomicAdd(&hist[s1], 1u); }
            if (ec.z > 0) { cntE++; sumOE += oc.z; atomicAdd(&hist[s2], 1u); }
            if (ec.w > 0) { cntE++; sumOE += oc.w; atomicAdd(&hist[s3], 1u); }
            if (u < 3) { oc = on; ec = en; sc = sn; }
        }
        // per-wave chunk-sum flush: one float atomic per (wave, chunk)
        const float w0 = waveReduceSumF(sE0);
        const float w1 = waveReduceSumF(sE1);
        if (lane == 0) {
            const int c0 = superBase >> CHUNK_LOG;
            atomicAdd(&csums[c0], w0);
            atomicAdd(&csums[c0 + 1], w1);
        }
    } else {
        // tail path (not hit for N = 16M)
        for (int k = 0; k < SUBCH; ++k) {
            const int cbase = superBase + k * CHUNK;
            if (cbase >= N) break;
            const int end = (cbase + CHUNK < N) ? cbase + CHUNK : N;
            float s = 0.f;
            for (int i = cbase + (int)threadIdx.x; i < end; i += BLK) {
                const float o = outs[i];
                const int e = te[i];
                int sg = tt[i]; sg = sg < 0 ? -sg : sg;
                s += __expf(o);
                if (e > 0) { cntE++; sumOE += o; atomicAdd(&hist[sg], 1u); }
            }
            const float w = waveReduceSumF(s);
            if (lane == 0 && w != 0.f) atomicAdd(&csums[cbase >> CHUNK_LOG], w);
        }
    }

    __syncthreads();  // the only block barrier: hist complete

    for (int t = threadIdx.x; t < NUM_SEGS; t += BLK) {
        const unsigned h = hist[t];
        if (h) atomicAdd(&seg_cnt[t], h);
    }

    // block-reduce E stats
    const float wOE = waveReduceSumF(sumOE);
    const unsigned wC = waveReduceSumU(cntE);
    if (lane == 0) { redF[wid] = wOE; redU[wid] = wC; }
    __syncthreads();
    if (threadIdx.x == 0) {
        float oe = 0.f; unsigned c = 0u;
#pragma unroll
        for (int j = 0; j < NWAVE; ++j) { oe += redF[j]; c += redU[j]; }
        atomicAdd(loss1, (double)oe);
        atomicAdd(obs, c);
    }
}

// ---------------- pass 2 (fused): backward last-idx search + prefix + finalize
// Block t: scan chunks from the end until segment t is found (random data:
// always the last chunk, L2-hot for all 1024 blocks). Then fp64 prefix over
// csums[0..c), fp32 in-chunk exp-sum to LI, V*cnt, ticket-finalize.
__global__ __launch_bounds__(SEGBLK) void seg_final_kernel(
    const float* __restrict__ outs, const int* __restrict__ tt,
    const float* __restrict__ csums, const unsigned* __restrict__ seg_cnt,
    const double* __restrict__ loss1, double* __restrict__ loss2,
    const unsigned* __restrict__ obs, unsigned* __restrict__ done,
    float* __restrict__ out, int N, int nChunks) {
    __shared__ double redD[SEGBLK / 64];
    __shared__ float redF[SEGBLK / 64];
    __shared__ int redI[SEGBLK / 64];
    __shared__ int s_li;

    const int t = blockIdx.x;
    const unsigned cnt = seg_cnt[t];
    const int lane = threadIdx.x & 63, wid = threadIdx.x >> 6;

    if (cnt != 0u) {  // cnt==0 segments contribute 0
        // ---- backward search for the last occurrence of segment t ----
        int c = nChunks - 1;
        int LI = -1;
        for (;;) {
            const int base = c << CHUNK_LOG;
            const int end = (base + CHUNK < N) ? base + CHUNK : N;
            const int span = end - base;
            const int qspan = span & ~3;  // int4-aligned portion
            int li = -1;
            for (int i = base + ((int)threadIdx.x << 2); i < base + qspan;
                 i += SEGBLK * 4) {
                const int4 sv = *reinterpret_cast<const int4*>(tt + i);
                const int s0 = sv.x < 0 ? -sv.x : sv.x;
                const int s1 = sv.y < 0 ? -sv.y : sv.y;
                const int s2 = sv.z < 0 ? -sv.z : sv.z;
                const int s3 = sv.w < 0 ? -sv.w : sv.w;
                if (s3 == t) li = i + 3;
                else if (s2 == t) li = i + 2;
                else if (s1 == t) li = i + 1;
                else if (s0 == t) li = i;
                // ascending i => later assignment always larger
            }
            for (int i = base + qspan + (int)threadIdx.x; i < end; i += SEGBLK) {
                int s = tt[i]; s = s < 0 ? -s : s;
                if (s == t && i > li) li = i;
            }
            li = waveReduceMaxI(li);
            if (lane == 0) redI[wid] = li;
            __syncthreads();
            if (threadIdx.x == 0) {
                int m = redI[0];
#pragma unroll
                for (int j = 1; j < SEGBLK / 64; ++j) m = redI[j] > m ? redI[j] : m;
                s_li = m;
            }
            __syncthreads();
            LI = s_li;
            if (LI >= 0 || --c < 0) break;
        }

        if (LI >= 0) {
            // fp64 exclusive prefix of chunk sums [0, c)
            double p = 0.0;
            for (int j = threadIdx.x; j < c; j += SEGBLK) p += (double)csums[j];
            p = waveReduceSumD(p);
            if (lane == 0) redD[wid] = p;

            // fp32 in-chunk exp-sum up to and including LI
            const int base = c << CHUNK_LOG;
            float fs = 0.f;
            for (int i = base + (int)threadIdx.x; i <= LI; i += SEGBLK)
                fs += __expf(outs[i]);
            fs = waveReduceSumF(fs);
            if (lane == 0) redF[wid] = fs;
            __syncthreads();
            if (threadIdx.x == 0) {
                double pre = 0.0;
                float fsum = 0.f;
#pragma unroll
                for (int j = 0; j < SEGBLK / 64; ++j) { pre += redD[j]; fsum += redF[j]; }
                double sm = log(pre + (double)fsum);  // monotone cumsum => max at LI
                if (sm < 0.0) sm = 0.0;               // jnp.maximum(..., 0.0)
                atomicAdd(loss2, sm * (double)cnt);
            }
        }
    }

    // done-ticket: last block finalizes (no separate final kernel)
    if (threadIdx.x == 0) {
        __threadfence();
        const unsigned d = atomicAdd(done, 1u);
        if (d == (unsigned)(gridDim.x - 1)) {
            const double l2 = atomicAdd(loss2, 0.0);            // atomic read
            const double l1 = *(volatile const double*)loss1;   // prior dispatch
            const unsigned o = *(volatile const unsigned*)obs;
            out[0] = (float)((l2 - l1) / (double)o);
        }
    }
}

extern "C" void kernel_launch(void* const* d_in, const int* in_sizes, int n_in,
                              void* d_out, int out_size, void* d_ws, size_t ws_size,
                              hipStream_t stream) {
    const float* outs = (const float*)d_in[0];
    const int* te = (const int*)d_in[1];
    const int* tt = (const int*)d_in[2];
    const int N = in_sizes[0];
    float* out = (float*)d_out;

    const int nChunks = (N + CHUNK - 1) / CHUNK;

    char* ws = (char*)d_ws;
    double* d_loss1 = (double*)ws;                        // 1 double
    double* d_loss2 = d_loss1 + 1;                        // 1 double
    float* d_csums = (float*)(ws + 16);                   // nChunks floats
    unsigned* d_segcnt = (unsigned*)(d_csums + nChunks);  // NUM_SEGS u32
    unsigned* d_obs = d_segcnt + NUM_SEGS;
    unsigned* d_done = d_obs + 1;

    const int initThreads = (nChunks > NUM_SEGS ? nChunks : NUM_SEGS);
    init_kernel<<<(initThreads + 255) / 256, 256, 0, stream>>>(
        d_segcnt, d_csums, nChunks, d_obs, d_loss1, d_loss2, d_done);
    const int nSuper = (N + SUPER - 1) / SUPER;
    pass1_kernel<<<nSuper, BLK, 0, stream>>>(outs, te, tt, N, nChunks, d_csums,
                                             d_segcnt, d_obs, d_loss1);
    seg_final_kernel<<<NUM_SEGS, SEGBLK, 0, stream>>>(
        outs, tt, d_csums, d_segcnt, d_loss1, d_loss2, d_obs, d_done, out, N,
        nChunks);
}